// Round 14
// baseline (133.147 us; speedup 1.0000x reference)
//
#include <hip/hip_runtime.h>
#include <math.h>
#include <limits.h>

// Problem constants (match reference)
#define BD 4
#define ZD 40
#define YD 1024
#define XD 1024
#define BZYX (167772160)   // BD*ZD*YD*XD

constexpr int BLOCK = 256;
constexpr unsigned SMALL_LOG = 19;                  // 512k slots * 8B = 4 MB
constexpr unsigned long long EMPTY64 = ~0ull;
constexpr size_t OCC_BYTES = (size_t)1 << (SMALL_LOG - 3);   // 64 KB slot-occupancy bitmap

typedef unsigned uvec4 __attribute__((ext_vector_type(4)));

__device__ __forceinline__ unsigned hash_mix(unsigned x) {
    x ^= x >> 16; x *= 0x7feb352dU;
    x ^= x >> 15; x *= 0x846ca68bU;
    x ^= x >> 16;
    return x;
}

__device__ __forceinline__ float smooth_l1(float d) {
    float ad = fabsf(d);
    return (ad < 1.0f) ? 0.5f * d * d : ad - 0.5f;
}

__device__ __forceinline__ float logaddexp0(float logit) {
    return (logit > 0.0f) ? (logit + log1pf(expf(-logit))) : log1pf(expf(logit));
}

// Clear bm + occ + counter (one contiguous region).
__global__ void clear_bitmap(uvec4* __restrict__ bmv, int bmW4) {
    const uvec4 z = (uvec4)(0u);
    const int stride = gridDim.x * blockDim.x;
    for (int k = blockIdx.x * blockDim.x + threadIdx.x; k < bmW4; k += stride)
        bmv[k] = z;
}

// Fused: set membership bits, emit compact cell id per lidar point, and
// 0xFF-fill the small row table (independent buffer; hides under atomics).
__global__ void build_bitmap(const int4* __restrict__ li, int Nl,
                             unsigned* __restrict__ bm,
                             unsigned* __restrict__ cells,
                             uvec4* __restrict__ stv, int stW4) {
    const int gid = blockIdx.x * blockDim.x + threadIdx.x;
    if (gid < Nl) {
        int4 v = li[gid];  // [b,z,y,x]
        unsigned cell = ((unsigned)(v.x * ZD + v.y) * YD + v.z) * XD + v.w;
        cells[gid] = cell;
        atomicOr(&bm[cell >> 5], 1u << (cell & 31));
    }
    const uvec4 f = (uvec4)(~0u);
    const int stride = gridDim.x * blockDim.x;
    for (int k = gid; k < stW4; k += stride)
        stv[k] = f;
}

// Per radar point: membership via bitmap windows, argmin tie-break via masks,
// occ/cnt/off partial sums, matched cell -> mcell[i] + CAS-insert into stab
// (+ slot-occupancy bit for scan's fast reject).
__global__ void __launch_bounds__(BLOCK)
main_match(const float4* __restrict__ pf, const float* __restrict__ occ,
           const int4* __restrict__ ri, const unsigned* __restrict__ bm,
           unsigned long long* __restrict__ stab, unsigned* __restrict__ occbm,
           unsigned smask, const int* __restrict__ Rptr, int Nr,
           int* __restrict__ mcell, double* __restrict__ partials) {
    const int R = *Rptr;
    const int i = blockIdx.x * BLOCK + threadIdx.x;
    double occ_s = 0.0, cnt_s = 0.0, off_s = 0.0;

    if (i < Nr) {
        int4 rib = ri[i];
        const int b = rib.x, z = rib.y, y = rib.z, x = rib.w;
        int mc = -1;
        float m = 0.0f;
        int sx = 0, sy = 0, sz = 0;
        bool matched = false;

        if (R == 1) {
            // Gather all 27 membership bits with 9 independent u64 window loads.
            const int xa = max(x - 1, 0);
            const int xc = min(x + 1, XD - 1);
            const int sa = x - xa;        // shift for dx=0
            const int sc = xc - xa;       // shift for dx=+1
            unsigned hm = 0;
#pragma unroll
            for (int dz = -1; dz <= 1; ++dz) {
                const int zz = min(max(z + dz, 0), ZD - 1);
#pragma unroll
                for (int dy = -1; dy <= 1; ++dy) {
                    const int yy = min(max(y + dy, 0), YD - 1);
                    const unsigned n0 =
                        ((unsigned)(b * ZD + zz) * YD + yy) * XD + (unsigned)xa;
                    const unsigned q = n0 >> 5;
                    const int r = n0 & 31;
                    unsigned long long w =
                        ((unsigned long long)bm[q + 1] << 32) | bm[q];
                    w >>= r;
                    const int k0 = (dz + 1) * 9 + (dy + 1) * 3;
                    hm |= ((unsigned)(w & 1)) << (k0 + 0);
                    hm |= ((unsigned)((w >> sa) & 1)) << (k0 + 1);
                    hm |= ((unsigned)((w >> sc) & 1)) << (k0 + 2);
                }
            }
            // argmin(dL1) with first-k tie-break: distance-class masks.
            const unsigned M0 = 1u << 13;
            const unsigned M1 = (1u << 4) | (1u << 10) | (1u << 12) |
                                (1u << 14) | (1u << 16) | (1u << 22);
            const unsigned M2 = (1u << 1) | (1u << 3) | (1u << 5) | (1u << 7) |
                                (1u << 9) | (1u << 11) | (1u << 15) | (1u << 17) |
                                (1u << 19) | (1u << 21) | (1u << 23) | (1u << 25);
            int bk = -1;
            if (hm & M0)       bk = 13;
            else if (hm & M1)  bk = __ffs((int)(hm & M1)) - 1;
            else if (hm & M2)  bk = __ffs((int)(hm & M2)) - 1;
            else if (hm)       bk = __ffs((int)hm) - 1;   // distance-3 remainder
            if (bk >= 0) {
                matched = true;
                const int dz = bk / 9 - 1, dy = (bk / 3) % 3 - 1, dx = bk % 3 - 1;
                sz = min(max(z + dz, 0), ZD - 1);
                sy = min(max(y + dy, 0), YD - 1);
                sx = min(max(x + dx, 0), XD - 1);
            }
        } else {
            // Generic R: ordered triple loop (k ascending) with strict '<' update.
            int bestd = INT_MAX;
            for (int dz = -R; dz <= R; ++dz) {
                const int zz = min(max(z + dz, 0), ZD - 1);
                const int adz = abs(dz);
                for (int dy = -R; dy <= R; ++dy) {
                    const int yy = min(max(y + dy, 0), YD - 1);
                    const int adzy = adz + abs(dy);
                    for (int dx = -R; dx <= R; ++dx) {
                        const int d = adzy + abs(dx);
                        if (d >= bestd) continue;
                        const int xx = min(max(x + dx, 0), XD - 1);
                        const unsigned cell =
                            ((unsigned)(b * ZD + zz) * YD + yy) * XD + xx;
                        if ((bm[cell >> 5] >> (cell & 31)) & 1u) {
                            bestd = d; matched = true;
                            sz = zz; sy = yy; sx = xx;
                        }
                    }
                }
            }
        }

        if (matched) {
            m = 1.0f;
            cnt_s = 1.0;
            const unsigned cell = ((unsigned)(b * ZD + sz) * YD + sy) * XD + sx;
            mc = (int)cell;
            const float4 p = pf[i];
            off_s = (double)(smooth_l1(p.x - (float)(sx - x)) +
                             smooth_l1(p.y - (float)(sy - y)) +
                             smooth_l1(p.z - (float)(sz - z)));
            // Insert selected cell into stab (row filled by lidar_scan).
            const unsigned long long desired =
                ((unsigned long long)cell << 32) | 0xFFFFFFFFull;
            unsigned s = hash_mix(cell) & smask;
            bool claimed = false;
            while (true) {
                unsigned long long old = atomicCAS(&stab[s], EMPTY64, desired);
                if (old == EMPTY64) { claimed = true; break; }
                if ((unsigned)(old >> 32) == cell) break;
                s = (s + 1) & smask;
            }
            // Claimer marks the slot-occupancy bit (scan's fast reject).
            if (claimed) atomicOr(&occbm[s >> 5], 1u << (s & 31));
        }
        mcell[i] = mc;
        const float logit = occ[i];
        occ_s = (double)(logaddexp0(logit) - logit * m);
    }

    __shared__ double sh[3][BLOCK];
    const int tid = threadIdx.x;
    sh[0][tid] = occ_s; sh[1][tid] = cnt_s; sh[2][tid] = off_s;
    __syncthreads();
    for (int s = BLOCK / 2; s > 0; s >>= 1) {
        if (tid < s) {
            sh[0][tid] += sh[0][tid + s];
            sh[1][tid] += sh[1][tid + s];
            sh[2][tid] += sh[2][tid + s];
        }
        __syncthreads();
    }
    if (tid == 0) {
        partials[blockIdx.x * 4 + 0] = sh[0][0];
        partials[blockIdx.x * 4 + 1] = sh[1][0];
        partials[blockIdx.x * 4 + 2] = sh[2][0];
        partials[blockIdx.x * 4 + 3] = 0.0;   // feat comes from feat_pass
    }
}

// For every lidar point: fast-reject via 64KB slot-occupancy bitmap (L2-hot),
// else probe stab and atomicMin the lidar row.
__global__ void lidar_scan(const unsigned* __restrict__ cells, int Nl,
                           unsigned long long* __restrict__ stab,
                           const unsigned* __restrict__ occbm, unsigned smask) {
    int j = blockIdx.x * blockDim.x + threadIdx.x;
    if (j >= Nl) return;
    const unsigned cell = cells[j];
    unsigned s = hash_mix(cell) & smask;
    // occbit==0  <=>  stab[h(cell)] empty  =>  cell not inserted.
    if (!((occbm[s >> 5] >> (s & 31)) & 1u)) return;
    while (true) {
        const unsigned long long e = stab[s];
        if (e == EMPTY64) return;                       // cell not selected
        if ((unsigned)(e >> 32) == cell) {
            atomicMin((unsigned*)&stab[s], (unsigned)j); // low 32 bits = row
            return;
        }
        s = (s + 1) & smask;
    }
}

// Feature loss + last-block finalize (fused; saves one dispatch).
__global__ void __launch_bounds__(BLOCK)
feat_pass(const float4* __restrict__ pf, const int* __restrict__ mcell,
          const unsigned long long* __restrict__ stab, unsigned smask,
          const float4* __restrict__ lf, int Nr, double* __restrict__ fpart,
          const double* __restrict__ partials, unsigned* __restrict__ counter,
          int mblk, float* __restrict__ out) {
    const int i = blockIdx.x * BLOCK + threadIdx.x;
    double fs = 0.0;
    if (i < Nr) {
        const int mc = mcell[i];
        if (mc >= 0) {
            const unsigned cell = (unsigned)mc;
            unsigned s = hash_mix(cell) & smask;
            unsigned row = 0;
            while (true) {
                const unsigned long long e = stab[s];
                if ((unsigned)(e >> 32) == cell) { row = (unsigned)e; break; }
                s = (s + 1) & smask;
            }
            fs = (double)fabsf(pf[i].w - lf[row].w);
        }
    }
    __shared__ double sh[4][BLOCK];
    __shared__ bool isLast;
    const int tid = threadIdx.x;
    sh[0][tid] = fs;
    __syncthreads();
    for (int s = BLOCK / 2; s > 0; s >>= 1) {
        if (tid < s) sh[0][tid] += sh[0][tid + s];
        __syncthreads();
    }
    if (tid == 0) {
        fpart[blockIdx.x] = sh[0][0];
        __threadfence();
        const unsigned done = atomicAdd(counter, 1u);
        isLast = (done == gridDim.x - 1);
    }
    __syncthreads();
    if (!isLast) return;

    double a0 = 0, a1 = 0, a2 = 0, a3 = 0;
    for (int k = tid; k < mblk; k += BLOCK) {
        a0 += partials[k * 4 + 0];
        a1 += partials[k * 4 + 1];
        a2 += partials[k * 4 + 2];
    }
    for (int k = tid; k < (int)gridDim.x; k += BLOCK) a3 += fpart[k];
    __syncthreads();
    sh[0][tid] = a0; sh[1][tid] = a1; sh[2][tid] = a2; sh[3][tid] = a3;
    __syncthreads();
    for (int s = BLOCK / 2; s > 0; s >>= 1) {
        if (tid < s) {
            sh[0][tid] += sh[0][tid + s];
            sh[1][tid] += sh[1][tid + s];
            sh[2][tid] += sh[2][tid + s];
            sh[3][tid] += sh[3][tid + s];
        }
        __syncthreads();
    }
    if (tid == 0) {
        const double occ_loss = sh[0][0] / (double)Nr;
        const double cnt = sh[1][0];
        const double off_loss = sh[2][0] / fmax(cnt * 3.0, 1.0);
        const double feat_loss = sh[3][0] / fmax(cnt, 1.0);
        out[0] = (float)(0.2 * occ_loss + 1.0 * off_loss + 1.0 * feat_loss);
    }
}

// ---------------- Fallback: merged u64 hash table (ws too small) ----------------

__global__ void fb_insert(const int4* __restrict__ li, int Nl,
                          unsigned long long* __restrict__ tab, unsigned cmask) {
    int i = blockIdx.x * blockDim.x + threadIdx.x;
    if (i >= Nl) return;
    int4 v = li[i];
    const unsigned cell = ((unsigned)(v.x * ZD + v.y) * YD + v.z) * XD + v.w;
    const unsigned long long desired = ((unsigned long long)cell << 32) | (unsigned)i;
    unsigned s = hash_mix(cell) & cmask;
    unsigned probes = 0;
    while (probes++ <= cmask) {
        const unsigned long long old = atomicCAS(&tab[s], EMPTY64, desired);
        if (old == EMPTY64) return;
        if ((unsigned)(old >> 32) == cell) {
            atomicMin((unsigned*)&tab[s], (unsigned)i);
            return;
        }
        s = (s + 1) & cmask;
    }
}

__global__ void __launch_bounds__(BLOCK)
fb_main(const float4* __restrict__ pf, const float* __restrict__ occ,
        const int4* __restrict__ ri, const float4* __restrict__ lf,
        const unsigned long long* __restrict__ tab, unsigned cmask,
        const int* __restrict__ Rptr, int Nr, double* __restrict__ partials) {
    const int R = *Rptr;
    const int i = blockIdx.x * BLOCK + threadIdx.x;
    double occ_s = 0.0, cnt_s = 0.0, off_s = 0.0, feat_s = 0.0;
    if (i < Nr) {
        int4 rib = ri[i];
        const int b = rib.x, z = rib.y, y = rib.z, x = rib.w;
        int bestd = INT_MAX, bestRow = -1;
        int sx = 0, sy = 0, sz = 0;
        for (int dz = -R; dz <= R; ++dz) {
            const int zz = min(max(z + dz, 0), ZD - 1);
            const int adz = abs(dz);
            for (int dy = -R; dy <= R; ++dy) {
                const int yy = min(max(y + dy, 0), YD - 1);
                const int adzy = adz + abs(dy);
                for (int dx = -R; dx <= R; ++dx) {
                    const int d = adzy + abs(dx);
                    if (d >= bestd) continue;
                    const int xx = min(max(x + dx, 0), XD - 1);
                    const unsigned cell =
                        ((unsigned)(b * ZD + zz) * YD + yy) * XD + xx;
                    unsigned s = hash_mix(cell) & cmask;
                    int row = -1;
                    while (true) {
                        const unsigned long long e = tab[s];
                        if ((unsigned)(e >> 32) == cell) { row = (int)(unsigned)e; break; }
                        if (e == EMPTY64) break;
                        s = (s + 1) & cmask;
                    }
                    if (row >= 0) { bestd = d; bestRow = row; sz = zz; sy = yy; sx = xx; }
                }
            }
        }
        const float m = (bestRow >= 0) ? 1.0f : 0.0f;
        const float logit = occ[i];
        occ_s = (double)(logaddexp0(logit) - logit * m);
        if (bestRow >= 0) {
            cnt_s = 1.0;
            const float4 p = pf[i];
            off_s = (double)(smooth_l1(p.x - (float)(sx - x)) +
                             smooth_l1(p.y - (float)(sy - y)) +
                             smooth_l1(p.z - (float)(sz - z)));
            feat_s = (double)fabsf(p.w - lf[bestRow].w);
        }
    }
    __shared__ double sh[4][BLOCK];
    const int tid = threadIdx.x;
    sh[0][tid] = occ_s; sh[1][tid] = cnt_s; sh[2][tid] = off_s; sh[3][tid] = feat_s;
    __syncthreads();
    for (int s = BLOCK / 2; s > 0; s >>= 1) {
        if (tid < s) {
            sh[0][tid] += sh[0][tid + s];
            sh[1][tid] += sh[1][tid + s];
            sh[2][tid] += sh[2][tid + s];
            sh[3][tid] += sh[3][tid + s];
        }
        __syncthreads();
    }
    if (tid == 0) {
        partials[blockIdx.x * 4 + 0] = sh[0][0];
        partials[blockIdx.x * 4 + 1] = sh[1][0];
        partials[blockIdx.x * 4 + 2] = sh[2][0];
        partials[blockIdx.x * 4 + 3] = sh[3][0];
    }
}

__global__ void finalize_kernel(const double* __restrict__ partials,
                                const double* __restrict__ fpart, int nblk,
                                int Nr, float* __restrict__ out) {
    __shared__ double sh[4][BLOCK];
    const int tid = threadIdx.x;
    double a0 = 0, a1 = 0, a2 = 0, a3 = 0;
    for (int i = tid; i < nblk; i += BLOCK) {
        a0 += partials[i * 4 + 0];
        a1 += partials[i * 4 + 1];
        a2 += partials[i * 4 + 2];
        a3 += partials[i * 4 + 3] + fpart[i];
    }
    sh[0][tid] = a0; sh[1][tid] = a1; sh[2][tid] = a2; sh[3][tid] = a3;
    __syncthreads();
    for (int s = BLOCK / 2; s > 0; s >>= 1) {
        if (tid < s) {
            sh[0][tid] += sh[0][tid + s];
            sh[1][tid] += sh[1][tid + s];
            sh[2][tid] += sh[2][tid + s];
            sh[3][tid] += sh[3][tid + s];
        }
        __syncthreads();
    }
    if (tid == 0) {
        const double occ_loss = sh[0][0] / (double)Nr;
        const double cnt = sh[1][0];
        const double off_loss = sh[2][0] / fmax(cnt * 3.0, 1.0);
        const double feat_loss = sh[3][0] / fmax(cnt, 1.0);
        out[0] = (float)(0.2 * occ_loss + 1.0 * off_loss + 1.0 * feat_loss);
    }
}

extern "C" void kernel_launch(void* const* d_in, const int* in_sizes, int n_in,
                              void* d_out, int out_size, void* d_ws, size_t ws_size,
                              hipStream_t stream) {
    const float* pred_feat  = (const float*)d_in[0];   // (Nr,4)
    const float* pred_occ   = (const float*)d_in[1];   // (Nr,1,1)
    const int*   radar_idx  = (const int*)d_in[2];     // (Nr,4)
    const float* lidar_feat = (const float*)d_in[3];   // (Nl,4)
    const int*   lidar_idx  = (const int*)d_in[4];     // (Nl,4)
    const int*   Rptr       = (const int*)d_in[5];     // scalar (device)

    const int Nr = in_sizes[0] / 4;
    const int Nl = in_sizes[3] / 4;
    const int nblk  = (Nr + BLOCK - 1) / BLOCK;
    const int nblkL = (Nl + BLOCK - 1) / BLOCK;

    // Workspace layout: [bm | occ | counter] = contiguous cleared region,
    // then [stab (0xFF-filled by build) | cells | mcell | parts | fpart].
    size_t off = 0;
    auto alloc = [&](size_t n) { size_t o = off; off += (n + 255) & ~(size_t)255; return o; };
    const size_t bmBytes   = (size_t)BZYX / 8 + 64;          // bitmap + window pad
    const size_t stabBytes = (size_t)8 << SMALL_LOG;         // 4 MB
    const size_t bmOff   = alloc(bmBytes);
    const size_t occOff  = alloc(OCC_BYTES);
    const size_t ctrOff  = alloc(256);
    const size_t clearEnd = off;                             // bm + occ + counter
    const size_t stabOff = alloc(stabBytes);
    const size_t cellOff = alloc((size_t)Nl * 4);
    const size_t mcOff   = alloc((size_t)Nr * 4);
    const size_t pOff    = alloc((size_t)nblk * 4 * sizeof(double));
    const size_t fpOff   = alloc((size_t)nblk * sizeof(double));
    const size_t needD = off;

    char* ws = (char*)d_ws;
    if (needD <= ws_size) {
        unsigned*           bm    = (unsigned*)(ws + bmOff);
        unsigned*           occbm = (unsigned*)(ws + occOff);
        unsigned*           ctr   = (unsigned*)(ws + ctrOff);
        unsigned long long* stab  = (unsigned long long*)(ws + stabOff);
        unsigned*           cells = (unsigned*)(ws + cellOff);
        int*                mcell = (int*)(ws + mcOff);
        double*             parts = (double*)(ws + pOff);
        double*             fpart = (double*)(ws + fpOff);
        const unsigned smask = (1u << SMALL_LOG) - 1;
        const int stW4 = (int)(stabBytes / 16);

        clear_bitmap<<<4096, BLOCK, 0, stream>>>((uvec4*)ws, (int)(clearEnd / 16));
        build_bitmap<<<nblkL, BLOCK, 0, stream>>>(
            (const int4*)lidar_idx, Nl, bm, cells, (uvec4*)stab, stW4);
        main_match<<<nblk, BLOCK, 0, stream>>>(
            (const float4*)pred_feat, pred_occ, (const int4*)radar_idx,
            bm, stab, occbm, smask, Rptr, Nr, mcell, parts);
        lidar_scan<<<nblkL, BLOCK, 0, stream>>>(cells, Nl, stab, occbm, smask);
        feat_pass<<<nblk, BLOCK, 0, stream>>>(
            (const float4*)pred_feat, mcell, stab, smask,
            (const float4*)lidar_feat, Nr, fpart, parts, ctr, nblk, (float*)d_out);
    } else {
        // Fallback: merged u64 open-addressing table
        const size_t tailBytes = (size_t)nblk * 5 * sizeof(double) + 512;
        unsigned C = 1u << 22;
        while ((size_t)C * 8 + tailBytes > ws_size && C > (1u << 21)) C >>= 1;
        const unsigned cmask = C - 1;
        unsigned long long* tab = (unsigned long long*)ws;
        double* parts = (double*)(ws + ((size_t)C * 8 + 255 & ~(size_t)255));
        double* fpart = parts + (size_t)nblk * 4;

        hipError_t e1 = hipMemsetAsync(tab, 0xFF, (size_t)C * 8, stream); (void)e1;
        hipError_t e2 = hipMemsetAsync(fpart, 0x00, (size_t)nblk * sizeof(double), stream); (void)e2;

        fb_insert<<<nblkL, BLOCK, 0, stream>>>((const int4*)lidar_idx, Nl, tab, cmask);
        fb_main<<<nblk, BLOCK, 0, stream>>>(
            (const float4*)pred_feat, pred_occ, (const int4*)radar_idx,
            (const float4*)lidar_feat, tab, cmask, Rptr, Nr, parts);
        finalize_kernel<<<1, BLOCK, 0, stream>>>(parts, fpart, nblk, Nr, (float*)d_out);
    }
}

// Round 15
// 114.216 us; speedup vs baseline: 1.1657x; 1.1657x over previous
//
#include <hip/hip_runtime.h>
#include <math.h>
#include <limits.h>

// Problem constants (match reference)
#define BD 4
#define ZD 40
#define YD 1024
#define XD 1024
#define BZYX (167772160)   // BD*ZD*YD*XD

constexpr int BLOCK = 256;
constexpr unsigned SMALL_LOG = 19;                  // 512k slots * 8B = 4 MB
constexpr unsigned long long EMPTY64 = ~0ull;
constexpr size_t OCC_BYTES = (size_t)1 << (SMALL_LOG - 3);   // 64 KB slot-occupancy bitmap

typedef unsigned uvec4 __attribute__((ext_vector_type(4)));

__device__ __forceinline__ unsigned hash_mix(unsigned x) {
    x ^= x >> 16; x *= 0x7feb352dU;
    x ^= x >> 15; x *= 0x846ca68bU;
    x ^= x >> 16;
    return x;
}

__device__ __forceinline__ float smooth_l1(float d) {
    float ad = fabsf(d);
    return (ad < 1.0f) ? 0.5f * d * d : ad - 0.5f;
}

__device__ __forceinline__ float logaddexp0(float logit) {
    return (logit > 0.0f) ? (logit + log1pf(expf(-logit))) : log1pf(expf(logit));
}

// Clear bm + occ (one contiguous region).
__global__ void clear_bitmap(uvec4* __restrict__ bmv, int bmW4) {
    const uvec4 z = (uvec4)(0u);
    const int stride = gridDim.x * blockDim.x;
    for (int k = blockIdx.x * blockDim.x + threadIdx.x; k < bmW4; k += stride)
        bmv[k] = z;
}

// Fused: set membership bits, emit compact cell id per lidar point, and
// 0xFF-fill the small row table (independent buffer; hides under atomics).
__global__ void build_bitmap(const int4* __restrict__ li, int Nl,
                             unsigned* __restrict__ bm,
                             unsigned* __restrict__ cells,
                             uvec4* __restrict__ stv, int stW4) {
    const int gid = blockIdx.x * blockDim.x + threadIdx.x;
    if (gid < Nl) {
        int4 v = li[gid];  // [b,z,y,x]
        unsigned cell = ((unsigned)(v.x * ZD + v.y) * YD + v.z) * XD + v.w;
        cells[gid] = cell;
        atomicOr(&bm[cell >> 5], 1u << (cell & 31));
    }
    const uvec4 f = (uvec4)(~0u);
    const int stride = gridDim.x * blockDim.x;
    for (int k = gid; k < stW4; k += stride)
        stv[k] = f;
}

// Per radar point: membership via bitmap windows, argmin tie-break via masks,
// occ/cnt/off partial sums, matched cell -> mcell[i] + CAS-insert into stab
// (+ slot-occupancy bit for scan's fast reject).
__global__ void __launch_bounds__(BLOCK)
main_match(const float4* __restrict__ pf, const float* __restrict__ occ,
           const int4* __restrict__ ri, const unsigned* __restrict__ bm,
           unsigned long long* __restrict__ stab, unsigned* __restrict__ occbm,
           unsigned smask, const int* __restrict__ Rptr, int Nr,
           int* __restrict__ mcell, double* __restrict__ partials) {
    const int R = *Rptr;
    const int i = blockIdx.x * BLOCK + threadIdx.x;
    double occ_s = 0.0, cnt_s = 0.0, off_s = 0.0;

    if (i < Nr) {
        int4 rib = ri[i];
        const int b = rib.x, z = rib.y, y = rib.z, x = rib.w;
        int mc = -1;
        float m = 0.0f;
        int sx = 0, sy = 0, sz = 0;
        bool matched = false;

        if (R == 1) {
            // Gather all 27 membership bits with 9 independent u64 window loads.
            const int xa = max(x - 1, 0);
            const int xc = min(x + 1, XD - 1);
            const int sa = x - xa;        // shift for dx=0
            const int sc = xc - xa;       // shift for dx=+1
            unsigned hm = 0;
#pragma unroll
            for (int dz = -1; dz <= 1; ++dz) {
                const int zz = min(max(z + dz, 0), ZD - 1);
#pragma unroll
                for (int dy = -1; dy <= 1; ++dy) {
                    const int yy = min(max(y + dy, 0), YD - 1);
                    const unsigned n0 =
                        ((unsigned)(b * ZD + zz) * YD + yy) * XD + (unsigned)xa;
                    const unsigned q = n0 >> 5;
                    const int r = n0 & 31;
                    unsigned long long w =
                        ((unsigned long long)bm[q + 1] << 32) | bm[q];
                    w >>= r;
                    const int k0 = (dz + 1) * 9 + (dy + 1) * 3;
                    hm |= ((unsigned)(w & 1)) << (k0 + 0);
                    hm |= ((unsigned)((w >> sa) & 1)) << (k0 + 1);
                    hm |= ((unsigned)((w >> sc) & 1)) << (k0 + 2);
                }
            }
            // argmin(dL1) with first-k tie-break: distance-class masks.
            const unsigned M0 = 1u << 13;
            const unsigned M1 = (1u << 4) | (1u << 10) | (1u << 12) |
                                (1u << 14) | (1u << 16) | (1u << 22);
            const unsigned M2 = (1u << 1) | (1u << 3) | (1u << 5) | (1u << 7) |
                                (1u << 9) | (1u << 11) | (1u << 15) | (1u << 17) |
                                (1u << 19) | (1u << 21) | (1u << 23) | (1u << 25);
            int bk = -1;
            if (hm & M0)       bk = 13;
            else if (hm & M1)  bk = __ffs((int)(hm & M1)) - 1;
            else if (hm & M2)  bk = __ffs((int)(hm & M2)) - 1;
            else if (hm)       bk = __ffs((int)hm) - 1;   // distance-3 remainder
            if (bk >= 0) {
                matched = true;
                const int dz = bk / 9 - 1, dy = (bk / 3) % 3 - 1, dx = bk % 3 - 1;
                sz = min(max(z + dz, 0), ZD - 1);
                sy = min(max(y + dy, 0), YD - 1);
                sx = min(max(x + dx, 0), XD - 1);
            }
        } else {
            // Generic R: ordered triple loop (k ascending) with strict '<' update.
            int bestd = INT_MAX;
            for (int dz = -R; dz <= R; ++dz) {
                const int zz = min(max(z + dz, 0), ZD - 1);
                const int adz = abs(dz);
                for (int dy = -R; dy <= R; ++dy) {
                    const int yy = min(max(y + dy, 0), YD - 1);
                    const int adzy = adz + abs(dy);
                    for (int dx = -R; dx <= R; ++dx) {
                        const int d = adzy + abs(dx);
                        if (d >= bestd) continue;
                        const int xx = min(max(x + dx, 0), XD - 1);
                        const unsigned cell =
                            ((unsigned)(b * ZD + zz) * YD + yy) * XD + xx;
                        if ((bm[cell >> 5] >> (cell & 31)) & 1u) {
                            bestd = d; matched = true;
                            sz = zz; sy = yy; sx = xx;
                        }
                    }
                }
            }
        }

        if (matched) {
            m = 1.0f;
            cnt_s = 1.0;
            const unsigned cell = ((unsigned)(b * ZD + sz) * YD + sy) * XD + sx;
            mc = (int)cell;
            const float4 p = pf[i];
            off_s = (double)(smooth_l1(p.x - (float)(sx - x)) +
                             smooth_l1(p.y - (float)(sy - y)) +
                             smooth_l1(p.z - (float)(sz - z)));
            // Insert selected cell into stab (row filled by lidar_scan).
            const unsigned long long desired =
                ((unsigned long long)cell << 32) | 0xFFFFFFFFull;
            unsigned s = hash_mix(cell) & smask;
            bool claimed = false;
            while (true) {
                unsigned long long old = atomicCAS(&stab[s], EMPTY64, desired);
                if (old == EMPTY64) { claimed = true; break; }
                if ((unsigned)(old >> 32) == cell) break;
                s = (s + 1) & smask;
            }
            // Claimer marks the slot-occupancy bit (scan's fast reject).
            if (claimed) atomicOr(&occbm[s >> 5], 1u << (s & 31));
        }
        mcell[i] = mc;
        const float logit = occ[i];
        occ_s = (double)(logaddexp0(logit) - logit * m);
    }

    __shared__ double sh[3][BLOCK];
    const int tid = threadIdx.x;
    sh[0][tid] = occ_s; sh[1][tid] = cnt_s; sh[2][tid] = off_s;
    __syncthreads();
    for (int s = BLOCK / 2; s > 0; s >>= 1) {
        if (tid < s) {
            sh[0][tid] += sh[0][tid + s];
            sh[1][tid] += sh[1][tid + s];
            sh[2][tid] += sh[2][tid + s];
        }
        __syncthreads();
    }
    if (tid == 0) {
        partials[blockIdx.x * 4 + 0] = sh[0][0];
        partials[blockIdx.x * 4 + 1] = sh[1][0];
        partials[blockIdx.x * 4 + 2] = sh[2][0];
        partials[blockIdx.x * 4 + 3] = 0.0;   // feat comes from feat_pass
    }
}

// For every lidar point: fast-reject via 64KB slot-occupancy bitmap (L2-hot),
// else probe stab and atomicMin the lidar row.
__global__ void lidar_scan(const unsigned* __restrict__ cells, int Nl,
                           unsigned long long* __restrict__ stab,
                           const unsigned* __restrict__ occbm, unsigned smask) {
    int j = blockIdx.x * blockDim.x + threadIdx.x;
    if (j >= Nl) return;
    const unsigned cell = cells[j];
    unsigned s = hash_mix(cell) & smask;
    // occbit==0  <=>  stab[h(cell)] empty  =>  cell not inserted.
    if (!((occbm[s >> 5] >> (s & 31)) & 1u)) return;
    while (true) {
        const unsigned long long e = stab[s];
        if (e == EMPTY64) return;                       // cell not selected
        if ((unsigned)(e >> 32) == cell) {
            atomicMin((unsigned*)&stab[s], (unsigned)j); // low 32 bits = row
            return;
        }
        s = (s + 1) & smask;
    }
}

__global__ void __launch_bounds__(BLOCK)
feat_pass(const float4* __restrict__ pf, const int* __restrict__ mcell,
          const unsigned long long* __restrict__ stab, unsigned smask,
          const float4* __restrict__ lf, int Nr, double* __restrict__ fpart) {
    const int i = blockIdx.x * BLOCK + threadIdx.x;
    double fs = 0.0;
    if (i < Nr) {
        const int mc = mcell[i];
        if (mc >= 0) {
            const unsigned cell = (unsigned)mc;
            unsigned s = hash_mix(cell) & smask;
            unsigned row = 0;
            while (true) {
                const unsigned long long e = stab[s];
                if ((unsigned)(e >> 32) == cell) { row = (unsigned)e; break; }
                s = (s + 1) & smask;
            }
            fs = (double)fabsf(pf[i].w - lf[row].w);
        }
    }
    __shared__ double sh[BLOCK];
    const int tid = threadIdx.x;
    sh[tid] = fs;
    __syncthreads();
    for (int s = BLOCK / 2; s > 0; s >>= 1) {
        if (tid < s) sh[tid] += sh[tid + s];
        __syncthreads();
    }
    if (tid == 0) fpart[blockIdx.x] = sh[0];
}

// ---------------- Fallback: merged u64 hash table (ws too small) ----------------

__global__ void fb_insert(const int4* __restrict__ li, int Nl,
                          unsigned long long* __restrict__ tab, unsigned cmask) {
    int i = blockIdx.x * blockDim.x + threadIdx.x;
    if (i >= Nl) return;
    int4 v = li[i];
    const unsigned cell = ((unsigned)(v.x * ZD + v.y) * YD + v.z) * XD + v.w;
    const unsigned long long desired = ((unsigned long long)cell << 32) | (unsigned)i;
    unsigned s = hash_mix(cell) & cmask;
    unsigned probes = 0;
    while (probes++ <= cmask) {
        const unsigned long long old = atomicCAS(&tab[s], EMPTY64, desired);
        if (old == EMPTY64) return;
        if ((unsigned)(old >> 32) == cell) {
            atomicMin((unsigned*)&tab[s], (unsigned)i);
            return;
        }
        s = (s + 1) & cmask;
    }
}

__global__ void __launch_bounds__(BLOCK)
fb_main(const float4* __restrict__ pf, const float* __restrict__ occ,
        const int4* __restrict__ ri, const float4* __restrict__ lf,
        const unsigned long long* __restrict__ tab, unsigned cmask,
        const int* __restrict__ Rptr, int Nr, double* __restrict__ partials) {
    const int R = *Rptr;
    const int i = blockIdx.x * BLOCK + threadIdx.x;
    double occ_s = 0.0, cnt_s = 0.0, off_s = 0.0, feat_s = 0.0;
    if (i < Nr) {
        int4 rib = ri[i];
        const int b = rib.x, z = rib.y, y = rib.z, x = rib.w;
        int bestd = INT_MAX, bestRow = -1;
        int sx = 0, sy = 0, sz = 0;
        for (int dz = -R; dz <= R; ++dz) {
            const int zz = min(max(z + dz, 0), ZD - 1);
            const int adz = abs(dz);
            for (int dy = -R; dy <= R; ++dy) {
                const int yy = min(max(y + dy, 0), YD - 1);
                const int adzy = adz + abs(dy);
                for (int dx = -R; dx <= R; ++dx) {
                    const int d = adzy + abs(dx);
                    if (d >= bestd) continue;
                    const int xx = min(max(x + dx, 0), XD - 1);
                    const unsigned cell =
                        ((unsigned)(b * ZD + zz) * YD + yy) * XD + xx;
                    unsigned s = hash_mix(cell) & cmask;
                    int row = -1;
                    while (true) {
                        const unsigned long long e = tab[s];
                        if ((unsigned)(e >> 32) == cell) { row = (int)(unsigned)e; break; }
                        if (e == EMPTY64) break;
                        s = (s + 1) & cmask;
                    }
                    if (row >= 0) { bestd = d; bestRow = row; sz = zz; sy = yy; sx = xx; }
                }
            }
        }
        const float m = (bestRow >= 0) ? 1.0f : 0.0f;
        const float logit = occ[i];
        occ_s = (double)(logaddexp0(logit) - logit * m);
        if (bestRow >= 0) {
            cnt_s = 1.0;
            const float4 p = pf[i];
            off_s = (double)(smooth_l1(p.x - (float)(sx - x)) +
                             smooth_l1(p.y - (float)(sy - y)) +
                             smooth_l1(p.z - (float)(sz - z)));
            feat_s = (double)fabsf(p.w - lf[bestRow].w);
        }
    }
    __shared__ double sh[4][BLOCK];
    const int tid = threadIdx.x;
    sh[0][tid] = occ_s; sh[1][tid] = cnt_s; sh[2][tid] = off_s; sh[3][tid] = feat_s;
    __syncthreads();
    for (int s = BLOCK / 2; s > 0; s >>= 1) {
        if (tid < s) {
            sh[0][tid] += sh[0][tid + s];
            sh[1][tid] += sh[1][tid + s];
            sh[2][tid] += sh[2][tid + s];
            sh[3][tid] += sh[3][tid + s];
        }
        __syncthreads();
    }
    if (tid == 0) {
        partials[blockIdx.x * 4 + 0] = sh[0][0];
        partials[blockIdx.x * 4 + 1] = sh[1][0];
        partials[blockIdx.x * 4 + 2] = sh[2][0];
        partials[blockIdx.x * 4 + 3] = sh[3][0];
    }
}

// ---------------- Finalize (separate kernel — fused variant measured +11-20us) ----

__global__ void finalize_kernel(const double* __restrict__ partials,
                                const double* __restrict__ fpart, int nblk,
                                int Nr, float* __restrict__ out) {
    __shared__ double sh[4][BLOCK];
    const int tid = threadIdx.x;
    double a0 = 0, a1 = 0, a2 = 0, a3 = 0;
    for (int i = tid; i < nblk; i += BLOCK) {
        a0 += partials[i * 4 + 0];
        a1 += partials[i * 4 + 1];
        a2 += partials[i * 4 + 2];
        a3 += partials[i * 4 + 3] + fpart[i];
    }
    sh[0][tid] = a0; sh[1][tid] = a1; sh[2][tid] = a2; sh[3][tid] = a3;
    __syncthreads();
    for (int s = BLOCK / 2; s > 0; s >>= 1) {
        if (tid < s) {
            sh[0][tid] += sh[0][tid + s];
            sh[1][tid] += sh[1][tid + s];
            sh[2][tid] += sh[2][tid + s];
            sh[3][tid] += sh[3][tid + s];
        }
        __syncthreads();
    }
    if (tid == 0) {
        const double occ_loss = sh[0][0] / (double)Nr;
        const double cnt = sh[1][0];
        const double off_loss = sh[2][0] / fmax(cnt * 3.0, 1.0);
        const double feat_loss = sh[3][0] / fmax(cnt, 1.0);
        out[0] = (float)(0.2 * occ_loss + 1.0 * off_loss + 1.0 * feat_loss);
    }
}

extern "C" void kernel_launch(void* const* d_in, const int* in_sizes, int n_in,
                              void* d_out, int out_size, void* d_ws, size_t ws_size,
                              hipStream_t stream) {
    const float* pred_feat  = (const float*)d_in[0];   // (Nr,4)
    const float* pred_occ   = (const float*)d_in[1];   // (Nr,1,1)
    const int*   radar_idx  = (const int*)d_in[2];     // (Nr,4)
    const float* lidar_feat = (const float*)d_in[3];   // (Nl,4)
    const int*   lidar_idx  = (const int*)d_in[4];     // (Nl,4)
    const int*   Rptr       = (const int*)d_in[5];     // scalar (device)

    const int Nr = in_sizes[0] / 4;
    const int Nl = in_sizes[3] / 4;
    const int nblk  = (Nr + BLOCK - 1) / BLOCK;
    const int nblkL = (Nl + BLOCK - 1) / BLOCK;

    // Workspace layout: [bm | occ] = contiguous cleared region,
    // then [stab (0xFF-filled by build) | cells | mcell | parts | fpart].
    size_t off = 0;
    auto alloc = [&](size_t n) { size_t o = off; off += (n + 255) & ~(size_t)255; return o; };
    const size_t bmBytes   = (size_t)BZYX / 8 + 64;          // bitmap + window pad
    const size_t stabBytes = (size_t)8 << SMALL_LOG;         // 4 MB
    const size_t bmOff   = alloc(bmBytes);
    const size_t occOff  = alloc(OCC_BYTES);
    const size_t clearEnd = off;                             // bm + occ
    const size_t stabOff = alloc(stabBytes);
    const size_t cellOff = alloc((size_t)Nl * 4);
    const size_t mcOff   = alloc((size_t)Nr * 4);
    const size_t pOff    = alloc((size_t)nblk * 4 * sizeof(double));
    const size_t fpOff   = alloc((size_t)nblk * sizeof(double));
    const size_t needD = off;

    char* ws = (char*)d_ws;
    if (needD <= ws_size) {
        unsigned*           bm    = (unsigned*)(ws + bmOff);
        unsigned*           occbm = (unsigned*)(ws + occOff);
        unsigned long long* stab  = (unsigned long long*)(ws + stabOff);
        unsigned*           cells = (unsigned*)(ws + cellOff);
        int*                mcell = (int*)(ws + mcOff);
        double*             parts = (double*)(ws + pOff);
        double*             fpart = (double*)(ws + fpOff);
        const unsigned smask = (1u << SMALL_LOG) - 1;
        const int stW4 = (int)(stabBytes / 16);

        clear_bitmap<<<4096, BLOCK, 0, stream>>>((uvec4*)ws, (int)(clearEnd / 16));
        build_bitmap<<<nblkL, BLOCK, 0, stream>>>(
            (const int4*)lidar_idx, Nl, bm, cells, (uvec4*)stab, stW4);
        main_match<<<nblk, BLOCK, 0, stream>>>(
            (const float4*)pred_feat, pred_occ, (const int4*)radar_idx,
            bm, stab, occbm, smask, Rptr, Nr, mcell, parts);
        lidar_scan<<<nblkL, BLOCK, 0, stream>>>(cells, Nl, stab, occbm, smask);
        feat_pass<<<nblk, BLOCK, 0, stream>>>(
            (const float4*)pred_feat, mcell, stab, smask,
            (const float4*)lidar_feat, Nr, fpart);
        finalize_kernel<<<1, BLOCK, 0, stream>>>(parts, fpart, nblk, Nr, (float*)d_out);
    } else {
        // Fallback: merged u64 open-addressing table
        const size_t tailBytes = (size_t)nblk * 5 * sizeof(double) + 512;
        unsigned C = 1u << 22;
        while ((size_t)C * 8 + tailBytes > ws_size && C > (1u << 21)) C >>= 1;
        const unsigned cmask = C - 1;
        unsigned long long* tab = (unsigned long long*)ws;
        double* parts = (double*)(ws + ((size_t)C * 8 + 255 & ~(size_t)255));
        double* fpart = parts + (size_t)nblk * 4;

        hipError_t e1 = hipMemsetAsync(tab, 0xFF, (size_t)C * 8, stream); (void)e1;
        hipError_t e2 = hipMemsetAsync(fpart, 0x00, (size_t)nblk * sizeof(double), stream); (void)e2;

        fb_insert<<<nblkL, BLOCK, 0, stream>>>((const int4*)lidar_idx, Nl, tab, cmask);
        fb_main<<<nblk, BLOCK, 0, stream>>>(
            (const float4*)pred_feat, pred_occ, (const int4*)radar_idx,
            (const float4*)lidar_feat, tab, cmask, Rptr, Nr, parts);
        finalize_kernel<<<1, BLOCK, 0, stream>>>(parts, fpart, nblk, Nr, (float*)d_out);
    }
}